// Round 2
// baseline (310.018 us; speedup 1.0000x reference)
//
#include <hip/hip_runtime.h>

#define N_NODES 50000
#define N_EDGES 800000
#define CAP 64
#define ROWS 16   // nodes per GEMM1 block; 50000 = 3125 * 16

typedef _Float16 f16;
typedef unsigned short u16;
typedef f16 f16x2 __attribute__((ext_vector_type(2)));
typedef f16 f16x4 __attribute__((ext_vector_type(4)));

// ---------------- build: bucket edges by dst (ushort src ids) ----------------
__global__ void k_build(const int* __restrict__ ei, int* __restrict__ cnt,
                        u16* __restrict__ bucket) {
    int e = blockIdx.x * blockDim.x + threadIdx.x;
    if (e >= N_EDGES) return;
    int s = ei[e];
    int d = ei[N_EDGES + e];
    int pos = atomicAdd(&cnt[d], 1);
    if (pos < CAP) bucket[d * CAP + pos] = (u16)s;
}

// ---------------- pack W2 / W-out pairs into f16x2 (wl, wr) ----------------
// w1p[k*42+j] = (Wl2[k][j], Wr2[k][j])                      117*42 entries
// w2p[k*48+j] = j<24 ? (Wlm[k][j],   Wrm[k][j])
//                    : (Wlv[k][j-24],Wrv[k][j-24])          42*48 entries
__global__ void k_packw(const float* __restrict__ Wl2, const float* __restrict__ Wr2,
                        const float* __restrict__ Wlm, const float* __restrict__ Wrm,
                        const float* __restrict__ Wlv, const float* __restrict__ Wrv,
                        f16x2* __restrict__ w1p, f16x2* __restrict__ w2p) {
    int t = blockIdx.x * blockDim.x + threadIdx.x;
    if (t < 117 * 42) {
        f16x2 w; w.x = (f16)Wl2[t]; w.y = (f16)Wr2[t];
        w1p[t] = w;
    }
    int t2 = t - 117 * 42;
    if (t2 >= 0 && t2 < 42 * 48) {
        int k = t2 / 48, j = t2 % 48;
        int o = (j < 24) ? j : j - 24;
        const float* L = (j < 24) ? Wlm : Wlv;
        const float* R = (j < 24) ? Wrm : Wrv;
        f16x2 w; w.x = (f16)L[k * 24 + o]; w.y = (f16)R[k * 24 + o];
        w2p[t2] = w;
    }
}

// ------- t1l = x@Wl1 (f16, stride 128, cols 117..127 zeroed)
// ------- t1r = x@Wr1 + b1 (fp32, stride 120, cols 117..119 zeroed) -------
__global__ __launch_bounds__(256) void k_gemm1(const float* __restrict__ x,
                        const float* __restrict__ Wl, const float* __restrict__ Wr,
                        const float* __restrict__ b1,
                        f16* __restrict__ t1l, float* __restrict__ t1r) {
    int base = blockIdx.x * ROWS;
    int t = threadIdx.x;
    __shared__ __align__(16) float xs[128][20];
    for (int idx = t; idx < ROWS * 128; idx += 256) {
        int r = idx >> 7, c = idx & 127;
        xs[c][r] = x[(size_t)base * 128 + idx];
    }
    __syncthreads();
    if (t < 234) {
        const float* Wc = (t < 117) ? (Wl + t) : (Wr + (t - 117));
        float acc[ROWS];
#pragma unroll
        for (int r = 0; r < ROWS; ++r) acc[r] = 0.f;
#pragma unroll 4
        for (int k = 0; k < 128; ++k) {
            float w = Wc[(size_t)k * 117];
            const float4* xv = (const float4*)&xs[k][0];
            float4 x0 = xv[0], x1 = xv[1], x2 = xv[2], x3 = xv[3];
            acc[0]  = fmaf(x0.x, w, acc[0]);  acc[1]  = fmaf(x0.y, w, acc[1]);
            acc[2]  = fmaf(x0.z, w, acc[2]);  acc[3]  = fmaf(x0.w, w, acc[3]);
            acc[4]  = fmaf(x1.x, w, acc[4]);  acc[5]  = fmaf(x1.y, w, acc[5]);
            acc[6]  = fmaf(x1.z, w, acc[6]);  acc[7]  = fmaf(x1.w, w, acc[7]);
            acc[8]  = fmaf(x2.x, w, acc[8]);  acc[9]  = fmaf(x2.y, w, acc[9]);
            acc[10] = fmaf(x2.z, w, acc[10]); acc[11] = fmaf(x2.w, w, acc[11]);
            acc[12] = fmaf(x3.x, w, acc[12]); acc[13] = fmaf(x3.y, w, acc[13]);
            acc[14] = fmaf(x3.z, w, acc[14]); acc[15] = fmaf(x3.w, w, acc[15]);
        }
        if (t < 117) {
#pragma unroll
            for (int r = 0; r < ROWS; ++r)
                t1l[(size_t)(base + r) * 128 + t] = (f16)acc[r];
        } else {
            int col = t - 117;
            float bb = b1[col];
#pragma unroll
            for (int r = 0; r < ROWS; ++r)
                t1r[(size_t)(base + r) * 120 + col] = acc[r] + bb;
        }
    } else if (t < 245) {          // zero-fill t1l pad cols 117..127
        int c = 117 + (t - 234);
#pragma unroll
        for (int r = 0; r < ROWS; ++r) t1l[(size_t)(base + r) * 128 + c] = (f16)0.f;
    } else if (t < 248) {          // zero-fill t1r pad cols 117..119
        int c = 117 + (t - 245);
#pragma unroll
        for (int r = 0; r < ROWS; ++r) t1r[(size_t)(base + r) * 120 + c] = 0.f;
    }
}

// ---- fused1: 2 nodes/wave. h1 = relu(gather(t1l)/deg + t1r); then
// ----         t2l = h1@Wl2 (f16), s2 = h1@Wr2 + b2.  grid = 25000, block = 64
__global__ __launch_bounds__(64) void k_fused1(
        const f16* __restrict__ t1l, const float* __restrict__ t1r,
        const int* __restrict__ cnt, const u16* __restrict__ bucket,
        const f16x2* __restrict__ w1p, const float* __restrict__ b2,
        f16* __restrict__ t2l, float* __restrict__ s2) {
    __shared__ __align__(16) float h1[2][120];
    int lane = threadIdx.x;
    int iA = blockIdx.x * 2, iB = iA + 1;
    int cA = cnt[iA], cB = cnt[iB];
    int nA = cA > CAP ? CAP : cA, nB = cB > CAP ? CAP : cB;
    int idsA = (int)bucket[(size_t)iA * CAP + lane];
    int idsB = (int)bucket[(size_t)iB * CAP + lane];
    int g = (lane < 30) ? 0 : 1;
    int d = lane - 30 * g;                 // qword index; valid < 30
    bool act = (lane < 60);
    int n_my = act ? (g ? nB : nA) : 0;
    int i_my = g ? iB : iA;
    float deg = fmaxf((float)(g ? cB : cA), 1.f);
    int dd = d < 31 ? d : 31;              // keep inactive-lane loads in-row
    int nmax = nA > nB ? nA : nB;
    float ax = 0.f, ay = 0.f, az = 0.f, aw = 0.f;
    const f16x4* src = (const f16x4*)t1l;  // 32 qwords per row
    for (int e0 = 0; e0 < nmax; e0 += 16) {
        f16x4 v[16];
#pragma unroll
        for (int u = 0; u < 16; ++u) {
            int e = e0 + u;
            int ra = __builtin_amdgcn_readlane(idsA, e & 63);
            int rb = __builtin_amdgcn_readlane(idsB, e & 63);
            int id = g ? rb : ra;
            id = (e < n_my) ? id : 0;
            v[u] = src[(size_t)id * 32 + dd];
        }
#pragma unroll
        for (int u = 0; u < 16; ++u) {
            int e = e0 + u;
            if (e < n_my) {
                ax += (float)v[u].x; ay += (float)v[u].y;
                az += (float)v[u].z; aw += (float)v[u].w;
            }
        }
    }
    if (act) {
        float4 s = ((const float4*)(t1r + (size_t)i_my * 120))[d];
        float4 hv;
        hv.x = fmaxf(ax / deg + s.x, 0.f);
        hv.y = fmaxf(ay / deg + s.y, 0.f);
        hv.z = fmaxf(az / deg + s.z, 0.f);
        hv.w = fmaxf(aw / deg + s.w, 0.f);
        *((float4*)&h1[g][4 * d]) = hv;
    }
    __syncthreads();
    int j = lane;
    if (j < 42) {
        float pA = 0.f, pB = 0.f, qA = 0.f, qB = 0.f;
        const float4* hA = (const float4*)&h1[0][0];
        const float4* hB = (const float4*)&h1[1][0];
#pragma unroll 4
        for (int kk = 0; kk < 29; ++kk) {       // k = 0..115
            float4 a = hA[kk], b = hB[kk];
            float av[4] = {a.x, a.y, a.z, a.w};
            float bv[4] = {b.x, b.y, b.z, b.w};
#pragma unroll
            for (int u = 0; u < 4; ++u) {
                int k = 4 * kk + u;
                f16x2 wv = w1p[k * 42 + j];
                float wl = (float)wv.x, wr = (float)wv.y;
                pA = fmaf(av[u], wl, pA); pB = fmaf(bv[u], wl, pB);
                qA = fmaf(av[u], wr, qA); qB = fmaf(bv[u], wr, qB);
            }
        }
        {   int k = 116;
            f16x2 wv = w1p[k * 42 + j];
            float wl = (float)wv.x, wr = (float)wv.y;
            float va = h1[0][k], vb = h1[1][k];
            pA = fmaf(va, wl, pA); pB = fmaf(vb, wl, pB);
            qA = fmaf(va, wr, qA); qB = fmaf(vb, wr, qB);
        }
        float bb = b2[j];
        t2l[(size_t)iA * 64 + j] = (f16)pA;
        t2l[(size_t)iB * 64 + j] = (f16)pB;
        s2[(size_t)iA * 42 + j] = qA + bb;
        s2[(size_t)iB * 42 + j] = qB + bb;
    }
}

// ---- fused2: 3 nodes/wave. h2 = relu(gather(t2l)/deg + s2); then
// ----         p = h2@[Wlm|Wlv] (f16), d_out self = h2@[Wrm|Wrv] + b.
// ----         grid = 16667, block = 64
__global__ __launch_bounds__(64) void k_fused2(
        const f16* __restrict__ t2l, const float* __restrict__ s2,
        const int* __restrict__ cnt, const u16* __restrict__ bucket,
        const f16x2* __restrict__ w2p,
        const float* __restrict__ bm, const float* __restrict__ bv,
        f16* __restrict__ p, float* __restrict__ out) {
    __shared__ __align__(16) float h2[3][48];
    int lane = threadIdx.x;
    int i0 = blockIdx.x * 3;
    int iA = i0, iB = i0 + 1, iC = i0 + 2;
    bool vA = iA < N_NODES, vB = iB < N_NODES, vC = iC < N_NODES;
    int cA = vA ? cnt[iA] : 0, cB = vB ? cnt[iB] : 0, cC = vC ? cnt[iC] : 0;
    int nA = cA > CAP ? CAP : cA, nB = cB > CAP ? CAP : cB, nC = cC > CAP ? CAP : cC;
    int idsA = vA ? (int)bucket[(size_t)iA * CAP + lane] : 0;
    int idsB = vB ? (int)bucket[(size_t)iB * CAP + lane] : 0;
    int idsC = vC ? (int)bucket[(size_t)iC * CAP + lane] : 0;
    int g = (lane < 21) ? 0 : (lane < 42 ? 1 : 2);
    int d = lane - 21 * g;                 // dword index; valid < 21 (lane 63 -> d 21)
    bool act = (lane < 63);
    int i_my = i0 + g;
    bool valid = act && (i_my < N_NODES);
    int n_my = valid ? (g == 0 ? nA : (g == 1 ? nB : nC)) : 0;
    float deg = fmaxf((float)(g == 0 ? cA : (g == 1 ? cB : cC)), 1.f);
    int nmax = nA > nB ? nA : nB; if (nC > nmax) nmax = nC;
    float ax = 0.f, ay = 0.f;
    const f16x2* src = (const f16x2*)t2l;  // 32 dwords per row
    for (int e0 = 0; e0 < nmax; e0 += 16) {
        f16x2 v[16];
#pragma unroll
        for (int u = 0; u < 16; ++u) {
            int e = e0 + u;
            int ra = __builtin_amdgcn_readlane(idsA, e & 63);
            int rb = __builtin_amdgcn_readlane(idsB, e & 63);
            int rc = __builtin_amdgcn_readlane(idsC, e & 63);
            int id = (g == 0) ? ra : ((g == 1) ? rb : rc);
            id = (e < n_my) ? id : 0;
            v[u] = src[(size_t)id * 32 + d];
        }
#pragma unroll
        for (int u = 0; u < 16; ++u) {
            int e = e0 + u;
            if (e < n_my) { ax += (float)v[u].x; ay += (float)v[u].y; }
        }
    }
    if (valid && d < 21) {
        float2 s = ((const float2*)(s2 + (size_t)i_my * 42))[d];
        h2[g][2 * d]     = fmaxf(ax / deg + s.x, 0.f);
        h2[g][2 * d + 1] = fmaxf(ay / deg + s.y, 0.f);
    }
    __syncthreads();
    int j = lane;
    if (j < 48) {
        int o = (j < 24) ? j : j - 24;
        float bias = (j < 24) ? bm[o] : bv[o];
        float pA = 0.f, pB = 0.f, pC = 0.f, qA = 0.f, qB = 0.f, qC = 0.f;
        const float4* hA = (const float4*)&h2[0][0];
        const float4* hB = (const float4*)&h2[1][0];
        const float4* hC = (const float4*)&h2[2][0];
#pragma unroll 2
        for (int kk = 0; kk < 10; ++kk) {       // k = 0..39
            float4 a = hA[kk], b = hB[kk], c = hC[kk];
            float av[4] = {a.x, a.y, a.z, a.w};
            float bv4[4] = {b.x, b.y, b.z, b.w};
            float cv[4] = {c.x, c.y, c.z, c.w};
#pragma unroll
            for (int u = 0; u < 4; ++u) {
                int k = 4 * kk + u;
                f16x2 wv = w2p[k * 48 + j];
                float wl = (float)wv.x, wr = (float)wv.y;
                pA = fmaf(av[u], wl, pA);  qA = fmaf(av[u], wr, qA);
                pB = fmaf(bv4[u], wl, pB); qB = fmaf(bv4[u], wr, qB);
                pC = fmaf(cv[u], wl, pC);  qC = fmaf(cv[u], wr, qC);
            }
        }
        for (int k = 40; k < 42; ++k) {
            f16x2 wv = w2p[k * 48 + j];
            float wl = (float)wv.x, wr = (float)wv.y;
            pA = fmaf(h2[0][k], wl, pA); qA = fmaf(h2[0][k], wr, qA);
            pB = fmaf(h2[1][k], wl, pB); qB = fmaf(h2[1][k], wr, qB);
            pC = fmaf(h2[2][k], wl, pC); qC = fmaf(h2[2][k], wr, qC);
        }
        size_t half = (j < 24) ? 0 : (size_t)N_NODES * 24;
        if (vA) { p[(size_t)iA * 64 + j] = (f16)pA; out[half + (size_t)iA * 24 + o] = qA + bias; }
        if (vB) { p[(size_t)iB * 64 + j] = (f16)pB; out[half + (size_t)iB * 24 + o] = qB + bias; }
        if (vC) { p[(size_t)iC * 64 + j] = (f16)pC; out[half + (size_t)iC * 24 + o] = qC + bias; }
    }
}

// ---- final: 2 nodes/wave, pure gather of p + RMW of self-term in d_out.
// ----        grid = 25000, block = 64
__global__ __launch_bounds__(64) void k_final(
        const f16* __restrict__ p, const int* __restrict__ cnt,
        const u16* __restrict__ bucket, float* __restrict__ out) {
    int lane = threadIdx.x;
    int iA = blockIdx.x * 2, iB = iA + 1;
    int cA = cnt[iA], cB = cnt[iB];
    int nA = cA > CAP ? CAP : cA, nB = cB > CAP ? CAP : cB;
    int idsA = (int)bucket[(size_t)iA * CAP + lane];
    int idsB = (int)bucket[(size_t)iB * CAP + lane];
    int g = (lane < 24) ? 0 : 1;
    int d = lane - 24 * g;                 // dword index; valid < 24
    bool act = (lane < 48);
    int n_my = act ? (g ? nB : nA) : 0;
    int i_my = g ? iB : iA;
    float deg = fmaxf((float)(g ? cB : cA), 1.f);
    int dd = d < 31 ? d : 31;
    int nmax = nA > nB ? nA : nB;
    float ax = 0.f, ay = 0.f;
    const f16x2* src = (const f16x2*)p;    // 32 dwords per row
    for (int e0 = 0; e0 < nmax; e0 += 16) {
        f16x2 v[16];
#pragma unroll
        for (int u = 0; u < 16; ++u) {
            int e = e0 + u;
            int ra = __builtin_amdgcn_readlane(idsA, e & 63);
            int rb = __builtin_amdgcn_readlane(idsB, e & 63);
            int id = g ? rb : ra;
            id = (e < n_my) ? id : 0;
            v[u] = src[(size_t)id * 32 + dd];
        }
#pragma unroll
        for (int u = 0; u < 16; ++u) {
            int e = e0 + u;
            if (e < n_my) { ax += (float)v[u].x; ay += (float)v[u].y; }
        }
    }
    if (act) {
        float mx = ax / deg, my = ay / deg;
        size_t addr = (d < 12) ? ((size_t)i_my * 24 + 2 * d)
                               : ((size_t)N_NODES * 24 + (size_t)i_my * 24 + 2 * (d - 12));
        float2 s = *(const float2*)(out + addr);
        float2 r; r.x = s.x + mx; r.y = s.y + my;
        *(float2*)(out + addr) = r;
    }
}

extern "C" void kernel_launch(void* const* d_in, const int* in_sizes, int n_in,
                              void* d_out, int out_size, void* d_ws, size_t ws_size,
                              hipStream_t stream) {
    const float* x   = (const float*)d_in[0];
    const int*   ei  = (const int*)d_in[1];
    const float* Wl1 = (const float*)d_in[2];
    const float* Wr1 = (const float*)d_in[3];
    const float* b1  = (const float*)d_in[4];
    const float* Wl2 = (const float*)d_in[5];
    const float* Wr2 = (const float*)d_in[6];
    const float* b2  = (const float*)d_in[7];
    const float* Wlm = (const float*)d_in[8];
    const float* Wrm = (const float*)d_in[9];
    const float* bm  = (const float*)d_in[10];
    const float* Wlv = (const float*)d_in[11];
    const float* Wrv = (const float*)d_in[12];
    const float* bv  = (const float*)d_in[13];
    float* out = (float*)d_out;

    // workspace layout (bytes):
    //   cnt    @ 0          : 200,000   (pad 204,800)
    //   bucket @ 204,800    : 50000*64*2  =  6,400,000 ->  6,604,800
    //   t1l    @ 6,604,800  : 50000*128*2 = 12,800,000 -> 19,404,800
    //   t1r    @ 19,404,800 : 50000*120*4 = 24,000,000 -> 43,404,800
    //   t2l    @ 43,404,800 : 50000*64*2  =  6,400,000 -> 49,804,800
    //   s2     @ 49,804,800 : 50000*42*4  =  8,400,000 -> 58,204,800
    //   p      @ 58,204,800 : 50000*64*2  =  6,400,000 -> 64,604,800
    //   w1p    @ 64,604,800 : 117*42*4    =     19,656 -> 64,624,640 (padded)
    //   w2p    @ 64,624,640 : 42*48*4     =      8,064 -> 64,632,704
    char* ws = (char*)d_ws;
    int*   cnt    = (int*)(ws);
    u16*   bucket = (u16*)(ws + 204800);
    f16*   t1l    = (f16*)(ws + 6604800);
    float* t1r    = (float*)(ws + 19404800);
    f16*   t2l    = (f16*)(ws + 43404800);
    float* s2     = (float*)(ws + 49804800);
    f16*   p      = (f16*)(ws + 58204800);
    f16x2* w1p    = (f16x2*)(ws + 64604800);
    f16x2* w2p    = (f16x2*)(ws + 64624640);

    hipMemsetAsync(cnt, 0, N_NODES * sizeof(int), stream);
    k_packw<<<28, 256, 0, stream>>>(Wl2, Wr2, Wlm, Wrm, Wlv, Wrv, w1p, w2p);
    k_build<<<(N_EDGES + 255) / 256, 256, 0, stream>>>(ei, cnt, bucket);
    k_gemm1<<<N_NODES / ROWS, 256, 0, stream>>>(x, Wl1, Wr1, b1, t1l, t1r);
    k_fused1<<<N_NODES / 2, 64, 0, stream>>>(t1l, t1r, cnt, bucket, w1p, b2, t2l, s2);
    k_fused2<<<(N_NODES + 2) / 3, 64, 0, stream>>>(t2l, s2, cnt, bucket,
                                                   w2p, bm, bv, p, out);
    k_final<<<N_NODES / 2, 64, 0, stream>>>(p, cnt, bucket, out);
}

// Round 3
// 275.664 us; speedup vs baseline: 1.1246x; 1.1246x over previous
//
#include <hip/hip_runtime.h>

#define N_NODES 50000
#define N_EDGES 800000
#define CAP 64

typedef _Float16 f16;
typedef unsigned short u16;
typedef f16 f16x2 __attribute__((ext_vector_type(2)));
typedef f16 f16x4 __attribute__((ext_vector_type(4)));
typedef f16 f16x8 __attribute__((ext_vector_type(8)));
typedef float f32x4 __attribute__((ext_vector_type(4)));

// ---------------- build: bucket edges by dst (ushort src ids) ----------------
__global__ void k_build(const int* __restrict__ ei, int* __restrict__ cnt,
                        u16* __restrict__ bucket) {
    int e = blockIdx.x * blockDim.x + threadIdx.x;
    if (e >= N_EDGES) return;
    int s = ei[e];
    int d = ei[N_EDGES + e];
    int pos = atomicAdd(&cnt[d], 1);
    if (pos < CAP) bucket[d * CAP + pos] = (u16)s;
}

// ---------------- pack weights ----------------
// w1p[k*42+j] = (Wl2[k][j], Wr2[k][j])                      117*42 entries
// w2p[k*48+j] = j<24 ? (Wlm[k][j],   Wrm[k][j])
//                    : (Wlv[k][j-24],Wrv[k][j-24])          42*48 entries
// w1b: MFMA B-fragments for [Wl1 | Wr1 | pad] as f16.
//   fragment f = nt*4+s (nt=0..14 N-tile, s=0..3 K-step), lane l, elem j:
//   w1b[(f*64+l)*8+j] = W[k = s*32 + (l>>4)*8 + j][col = nt*16 + (l&15)]
//   where col<117 -> Wl1, col<234 -> Wr1[col-117], else 0.
__global__ void k_packw(const float* __restrict__ Wl1, const float* __restrict__ Wr1,
                        const float* __restrict__ Wl2, const float* __restrict__ Wr2,
                        const float* __restrict__ Wlm, const float* __restrict__ Wrm,
                        const float* __restrict__ Wlv, const float* __restrict__ Wrv,
                        f16x2* __restrict__ w1p, f16x2* __restrict__ w2p,
                        f16* __restrict__ w1b) {
    int t = blockIdx.x * blockDim.x + threadIdx.x;
    if (t < 117 * 42) {
        f16x2 w; w.x = (f16)Wl2[t]; w.y = (f16)Wr2[t];
        w1p[t] = w;
    }
    int t2 = t - 117 * 42;
    if (t2 >= 0 && t2 < 42 * 48) {
        int k = t2 / 48, j = t2 % 48;
        int o = (j < 24) ? j : j - 24;
        const float* L = (j < 24) ? Wlm : Wlv;
        const float* R = (j < 24) ? Wrm : Wrv;
        f16x2 w; w.x = (f16)L[k * 24 + o]; w.y = (f16)R[k * 24 + o];
        w2p[t2] = w;
    }
    if (t < 15 * 4 * 64 * 8) {
        int f = t >> 9;          // fragment id 0..59
        int r = t & 511;
        int lane = r >> 3, j = r & 7;
        int nt = f >> 2, s = f & 3;
        int k = s * 32 + (lane >> 4) * 8 + j;
        int col = nt * 16 + (lane & 15);
        float v = 0.f;
        if (col < 117) v = Wl1[k * 117 + col];
        else if (col < 234) v = Wr1[k * 117 + (col - 117)];
        w1b[t] = (f16)v;
    }
}

// ------- MFMA gemm1: t1l = x@Wl1 (f16, stride 128, cols 117..127 zeroed)
// -------             t1r = x@Wr1 + b1 (fp32, stride 120, cols 117..119 zeroed)
// ------- 16 rows/block, 256 threads (4 waves); wave w does N-tiles w*4..
__global__ __launch_bounds__(256) void k_gemm1(const float* __restrict__ x,
                        const f16* __restrict__ w1b, const float* __restrict__ b1,
                        f16* __restrict__ t1l, float* __restrict__ t1r) {
    int base = blockIdx.x * 16;
    int t = threadIdx.x;
    __shared__ __align__(16) f16 xa[16 * 128];   // 4 KB, XOR-swizzled 16B chunks
    {   // stage x tile -> f16 LDS
        int row = t >> 4, kc = t & 15;           // kc: 8-elem chunk along K
        const float4* xp = (const float4*)(x + (size_t)(base + row) * 128 + kc * 8);
        float4 x0 = xp[0], x1 = xp[1];
        f16x8 hv;
        hv[0] = (f16)x0.x; hv[1] = (f16)x0.y; hv[2] = (f16)x0.z; hv[3] = (f16)x0.w;
        hv[4] = (f16)x1.x; hv[5] = (f16)x1.y; hv[6] = (f16)x1.z; hv[7] = (f16)x1.w;
        int byte = row * 256 + ((kc ^ (row & 7)) << 4);
        *(f16x8*)((char*)xa + byte) = hv;
    }
    __syncthreads();
    int lane = t & 63, w = t >> 6;
    int hi = lane >> 4, lo = lane & 15;
    f16x8 a[4];                                   // A fragments, resident
#pragma unroll
    for (int s = 0; s < 4; ++s) {
        int kchunk = s * 4 + hi;
        int byte = lo * 256 + ((kchunk ^ (lo & 7)) << 4);
        a[s] = *(const f16x8*)((const char*)xa + byte);
    }
    int ntiles = (w < 3) ? 4 : 3;                 // 15 N-tiles of 16 cols
    for (int i = 0; i < ntiles; ++i) {
        int nt = w * 4 + i;
        const f16x8* bp = (const f16x8*)w1b + (size_t)(nt * 4) * 64 + lane;
        f32x4 acc = {0.f, 0.f, 0.f, 0.f};
#pragma unroll
        for (int s = 0; s < 4; ++s)
            acc = __builtin_amdgcn_mfma_f32_16x16x32_f16(a[s], bp[s * 64], acc, 0, 0, 0);
        int gcol = nt * 16 + lo;
#pragma unroll
        for (int r = 0; r < 4; ++r) {
            int grow = base + hi * 4 + r;
            float val = acc[r];
            if (gcol < 117) {
                t1l[(size_t)grow * 128 + gcol] = (f16)val;
            } else if (nt == 7) {                 // t1l pad cols 117..127
                t1l[(size_t)grow * 128 + gcol] = (f16)0.f;
            }
            if (gcol >= 117) {
                int c2 = gcol - 117;
                if (c2 < 117)      t1r[(size_t)grow * 120 + c2] = val + b1[c2];
                else if (c2 < 120) t1r[(size_t)grow * 120 + c2] = 0.f;  // pad
            }
        }
    }
}

// ---- fused1: 2 nodes/wave. h1 = relu(gather(t1l)/deg + t1r); then
// ----         t2l = h1@Wl2 (f16), s2 = h1@Wr2 + b2.  grid = 25000, block = 64
__global__ __launch_bounds__(64) void k_fused1(
        const f16* __restrict__ t1l, const float* __restrict__ t1r,
        const int* __restrict__ cnt, const u16* __restrict__ bucket,
        const f16x2* __restrict__ w1p, const float* __restrict__ b2,
        f16* __restrict__ t2l, float* __restrict__ s2) {
    __shared__ __align__(16) float h1[2][120];
    int lane = threadIdx.x;
    int iA = blockIdx.x * 2, iB = iA + 1;
    int cA = cnt[iA], cB = cnt[iB];
    int nA = cA > CAP ? CAP : cA, nB = cB > CAP ? CAP : cB;
    int idsA = (int)bucket[(size_t)iA * CAP + lane];
    int idsB = (int)bucket[(size_t)iB * CAP + lane];
    int g = (lane < 30) ? 0 : 1;
    int d = lane - 30 * g;                 // qword index; valid < 30
    bool act = (lane < 60);
    int n_my = act ? (g ? nB : nA) : 0;
    int i_my = g ? iB : iA;
    float deg = fmaxf((float)(g ? cB : cA), 1.f);
    int dd = d < 31 ? d : 31;              // keep inactive-lane loads in-row
    int nmax = nA > nB ? nA : nB;
    float ax = 0.f, ay = 0.f, az = 0.f, aw = 0.f;
    const f16x4* src = (const f16x4*)t1l;  // 32 qwords per row
    for (int e0 = 0; e0 < nmax; e0 += 16) {
        f16x4 v[16];
#pragma unroll
        for (int u = 0; u < 16; ++u) {
            int e = e0 + u;
            int ra = __builtin_amdgcn_readlane(idsA, e & 63);
            int rb = __builtin_amdgcn_readlane(idsB, e & 63);
            int id = g ? rb : ra;
            id = (e < n_my) ? id : 0;
            v[u] = src[(size_t)id * 32 + dd];
        }
#pragma unroll
        for (int u = 0; u < 16; ++u) {
            int e = e0 + u;
            if (e < n_my) {
                ax += (float)v[u].x; ay += (float)v[u].y;
                az += (float)v[u].z; aw += (float)v[u].w;
            }
        }
    }
    if (act) {
        float4 s = ((const float4*)(t1r + (size_t)i_my * 120))[d];
        float4 hv;
        hv.x = fmaxf(ax / deg + s.x, 0.f);
        hv.y = fmaxf(ay / deg + s.y, 0.f);
        hv.z = fmaxf(az / deg + s.z, 0.f);
        hv.w = fmaxf(aw / deg + s.w, 0.f);
        *((float4*)&h1[g][4 * d]) = hv;
    }
    __syncthreads();
    int j = lane;
    if (j < 42) {
        float pA = 0.f, pB = 0.f, qA = 0.f, qB = 0.f;
        const float4* hA = (const float4*)&h1[0][0];
        const float4* hB = (const float4*)&h1[1][0];
#pragma unroll 4
        for (int kk = 0; kk < 29; ++kk) {       // k = 0..115
            float4 a = hA[kk], b = hB[kk];
            float av[4] = {a.x, a.y, a.z, a.w};
            float bv[4] = {b.x, b.y, b.z, b.w};
#pragma unroll
            for (int u = 0; u < 4; ++u) {
                int k = 4 * kk + u;
                f16x2 wv = w1p[k * 42 + j];
                float wl = (float)wv.x, wr = (float)wv.y;
                pA = fmaf(av[u], wl, pA); pB = fmaf(bv[u], wl, pB);
                qA = fmaf(av[u], wr, qA); qB = fmaf(bv[u], wr, qB);
            }
        }
        {   int k = 116;
            f16x2 wv = w1p[k * 42 + j];
            float wl = (float)wv.x, wr = (float)wv.y;
            float va = h1[0][k], vb = h1[1][k];
            pA = fmaf(va, wl, pA); pB = fmaf(vb, wl, pB);
            qA = fmaf(va, wr, qA); qB = fmaf(vb, wr, qB);
        }
        float bb = b2[j];
        t2l[(size_t)iA * 64 + j] = (f16)pA;
        t2l[(size_t)iB * 64 + j] = (f16)pB;
        s2[(size_t)iA * 42 + j] = qA + bb;
        s2[(size_t)iB * 42 + j] = qB + bb;
    }
}

// ---- fused2: 3 nodes/wave. h2 = relu(gather(t2l)/deg + s2); then
// ----         p = h2@[Wlm|Wlv] (f16), d_out self = h2@[Wrm|Wrv] + b.
// ----         grid = 16667, block = 64
__global__ __launch_bounds__(64) void k_fused2(
        const f16* __restrict__ t2l, const float* __restrict__ s2,
        const int* __restrict__ cnt, const u16* __restrict__ bucket,
        const f16x2* __restrict__ w2p,
        const float* __restrict__ bm, const float* __restrict__ bv,
        f16* __restrict__ p, float* __restrict__ out) {
    __shared__ __align__(16) float h2[3][48];
    int lane = threadIdx.x;
    int i0 = blockIdx.x * 3;
    int iA = i0, iB = i0 + 1, iC = i0 + 2;
    bool vA = iA < N_NODES, vB = iB < N_NODES, vC = iC < N_NODES;
    int cA = vA ? cnt[iA] : 0, cB = vB ? cnt[iB] : 0, cC = vC ? cnt[iC] : 0;
    int nA = cA > CAP ? CAP : cA, nB = cB > CAP ? CAP : cB, nC = cC > CAP ? CAP : cC;
    int idsA = vA ? (int)bucket[(size_t)iA * CAP + lane] : 0;
    int idsB = vB ? (int)bucket[(size_t)iB * CAP + lane] : 0;
    int idsC = vC ? (int)bucket[(size_t)iC * CAP + lane] : 0;
    int g = (lane < 21) ? 0 : (lane < 42 ? 1 : 2);
    int d = lane - 21 * g;                 // dword index; valid < 21 (lane 63 -> d 21)
    bool act = (lane < 63);
    int i_my = i0 + g;
    bool valid = act && (i_my < N_NODES);
    int n_my = valid ? (g == 0 ? nA : (g == 1 ? nB : nC)) : 0;
    float deg = fmaxf((float)(g == 0 ? cA : (g == 1 ? cB : cC)), 1.f);
    int nmax = nA > nB ? nA : nB; if (nC > nmax) nmax = nC;
    float ax = 0.f, ay = 0.f;
    const f16x2* src = (const f16x2*)t2l;  // 32 dwords per row
    for (int e0 = 0; e0 < nmax; e0 += 16) {
        f16x2 v[16];
#pragma unroll
        for (int u = 0; u < 16; ++u) {
            int e = e0 + u;
            int ra = __builtin_amdgcn_readlane(idsA, e & 63);
            int rb = __builtin_amdgcn_readlane(idsB, e & 63);
            int rc = __builtin_amdgcn_readlane(idsC, e & 63);
            int id = (g == 0) ? ra : ((g == 1) ? rb : rc);
            id = (e < n_my) ? id : 0;
            v[u] = src[(size_t)id * 32 + d];
        }
#pragma unroll
        for (int u = 0; u < 16; ++u) {
            int e = e0 + u;
            if (e < n_my) { ax += (float)v[u].x; ay += (float)v[u].y; }
        }
    }
    if (valid && d < 21) {
        float2 s = ((const float2*)(s2 + (size_t)i_my * 42))[d];
        h2[g][2 * d]     = fmaxf(ax / deg + s.x, 0.f);
        h2[g][2 * d + 1] = fmaxf(ay / deg + s.y, 0.f);
    }
    __syncthreads();
    int j = lane;
    if (j < 48) {
        int o = (j < 24) ? j : j - 24;
        float bias = (j < 24) ? bm[o] : bv[o];
        float pA = 0.f, pB = 0.f, pC = 0.f, qA = 0.f, qB = 0.f, qC = 0.f;
        const float4* hA = (const float4*)&h2[0][0];
        const float4* hB = (const float4*)&h2[1][0];
        const float4* hC = (const float4*)&h2[2][0];
#pragma unroll 2
        for (int kk = 0; kk < 10; ++kk) {       // k = 0..39
            float4 a = hA[kk], b = hB[kk], c = hC[kk];
            float av[4] = {a.x, a.y, a.z, a.w};
            float bv4[4] = {b.x, b.y, b.z, b.w};
            float cv[4] = {c.x, c.y, c.z, c.w};
#pragma unroll
            for (int u = 0; u < 4; ++u) {
                int k = 4 * kk + u;
                f16x2 wv = w2p[k * 48 + j];
                float wl = (float)wv.x, wr = (float)wv.y;
                pA = fmaf(av[u], wl, pA);  qA = fmaf(av[u], wr, qA);
                pB = fmaf(bv4[u], wl, pB); qB = fmaf(bv4[u], wr, qB);
                pC = fmaf(cv[u], wl, pC);  qC = fmaf(cv[u], wr, qC);
            }
        }
        for (int k = 40; k < 42; ++k) {
            f16x2 wv = w2p[k * 48 + j];
            float wl = (float)wv.x, wr = (float)wv.y;
            pA = fmaf(h2[0][k], wl, pA); qA = fmaf(h2[0][k], wr, qA);
            pB = fmaf(h2[1][k], wl, pB); qB = fmaf(h2[1][k], wr, qB);
            pC = fmaf(h2[2][k], wl, pC); qC = fmaf(h2[2][k], wr, qC);
        }
        size_t half = (j < 24) ? 0 : (size_t)N_NODES * 24;
        if (vA) { p[(size_t)iA * 64 + j] = (f16)pA; out[half + (size_t)iA * 24 + o] = qA + bias; }
        if (vB) { p[(size_t)iB * 64 + j] = (f16)pB; out[half + (size_t)iB * 24 + o] = qB + bias; }
        if (vC) { p[(size_t)iC * 64 + j] = (f16)pC; out[half + (size_t)iC * 24 + o] = qC + bias; }
    }
}

// ---- final: 2 nodes/wave, pure gather of p + RMW of self-term in d_out.
// ----        grid = 25000, block = 64
__global__ __launch_bounds__(64) void k_final(
        const f16* __restrict__ p, const int* __restrict__ cnt,
        const u16* __restrict__ bucket, float* __restrict__ out) {
    int lane = threadIdx.x;
    int iA = blockIdx.x * 2, iB = iA + 1;
    int cA = cnt[iA], cB = cnt[iB];
    int nA = cA > CAP ? CAP : cA, nB = cB > CAP ? CAP : cB;
    int idsA = (int)bucket[(size_t)iA * CAP + lane];
    int idsB = (int)bucket[(size_t)iB * CAP + lane];
    int g = (lane < 24) ? 0 : 1;
    int d = lane - 24 * g;                 // dword index; valid < 24
    bool act = (lane < 48);
    int n_my = act ? (g ? nB : nA) : 0;
    int i_my = g ? iB : iA;
    float deg = fmaxf((float)(g ? cB : cA), 1.f);
    int dd = d < 31 ? d : 31;
    int nmax = nA > nB ? nA : nB;
    float ax = 0.f, ay = 0.f;
    const f16x2* src = (const f16x2*)p;    // 32 dwords per row
    for (int e0 = 0; e0 < nmax; e0 += 16) {
        f16x2 v[16];
#pragma unroll
        for (int u = 0; u < 16; ++u) {
            int e = e0 + u;
            int ra = __builtin_amdgcn_readlane(idsA, e & 63);
            int rb = __builtin_amdgcn_readlane(idsB, e & 63);
            int id = g ? rb : ra;
            id = (e < n_my) ? id : 0;
            v[u] = src[(size_t)id * 32 + dd];
        }
#pragma unroll
        for (int u = 0; u < 16; ++u) {
            int e = e0 + u;
            if (e < n_my) { ax += (float)v[u].x; ay += (float)v[u].y; }
        }
    }
    if (act) {
        float mx = ax / deg, my = ay / deg;
        size_t addr = (d < 12) ? ((size_t)i_my * 24 + 2 * d)
                               : ((size_t)N_NODES * 24 + (size_t)i_my * 24 + 2 * (d - 12));
        float2 s = *(const float2*)(out + addr);
        float2 r; r.x = s.x + mx; r.y = s.y + my;
        *(float2*)(out + addr) = r;
    }
}

extern "C" void kernel_launch(void* const* d_in, const int* in_sizes, int n_in,
                              void* d_out, int out_size, void* d_ws, size_t ws_size,
                              hipStream_t stream) {
    const float* x   = (const float*)d_in[0];
    const int*   ei  = (const int*)d_in[1];
    const float* Wl1 = (const float*)d_in[2];
    const float* Wr1 = (const float*)d_in[3];
    const float* b1  = (const float*)d_in[4];
    const float* Wl2 = (const float*)d_in[5];
    const float* Wr2 = (const float*)d_in[6];
    const float* b2  = (const float*)d_in[7];
    const float* Wlm = (const float*)d_in[8];
    const float* Wrm = (const float*)d_in[9];
    const float* bm  = (const float*)d_in[10];
    const float* Wlv = (const float*)d_in[11];
    const float* Wrv = (const float*)d_in[12];
    const float* bv  = (const float*)d_in[13];
    float* out = (float*)d_out;

    // workspace layout (bytes):
    //   cnt    @ 0          : 200,000   (pad 204,800)
    //   bucket @ 204,800    : 50000*64*2  =  6,400,000 ->  6,604,800
    //   t1l    @ 6,604,800  : 50000*128*2 = 12,800,000 -> 19,404,800
    //   t1r    @ 19,404,800 : 50000*120*4 = 24,000,000 -> 43,404,800
    //   t2l    @ 43,404,800 : 50000*64*2  =  6,400,000 -> 49,804,800
    //   s2     @ 49,804,800 : 50000*42*4  =  8,400,000 -> 58,204,800
    //     (w1b B-fragments, 61,440 B, live only packw->gemm1, OVERLAYS s2:
    //      s2 is first written by k_fused1, after k_gemm1 has consumed w1b)
    //   p      @ 58,204,800 : 50000*64*2  =  6,400,000 -> 64,604,800
    //   w1p    @ 64,604,800 : 117*42*4    =     19,656 -> 64,624,640 (padded)
    //   w2p    @ 64,624,640 : 42*48*4     =      8,064 -> 64,632,704
    char* ws = (char*)d_ws;
    int*   cnt    = (int*)(ws);
    u16*   bucket = (u16*)(ws + 204800);
    f16*   t1l    = (f16*)(ws + 6604800);
    float* t1r    = (float*)(ws + 19404800);
    f16*   t2l    = (f16*)(ws + 43404800);
    float* s2     = (float*)(ws + 49804800);
    f16*   w1b    = (f16*)(ws + 49804800);   // overlays s2 (dead until fused1)
    f16*   p      = (f16*)(ws + 58204800);
    f16x2* w1p    = (f16x2*)(ws + 64604800);
    f16x2* w2p    = (f16x2*)(ws + 64624640);

    hipMemsetAsync(cnt, 0, N_NODES * sizeof(int), stream);
    k_packw<<<121, 256, 0, stream>>>(Wl1, Wr1, Wl2, Wr2, Wlm, Wrm, Wlv, Wrv,
                                     w1p, w2p, w1b);
    k_build<<<(N_EDGES + 255) / 256, 256, 0, stream>>>(ei, cnt, bucket);
    k_gemm1<<<N_NODES / 16, 256, 0, stream>>>(x, w1b, b1, t1l, t1r);
    k_fused1<<<N_NODES / 2, 64, 0, stream>>>(t1l, t1r, cnt, bucket, w1p, b2, t2l, s2);
    k_fused2<<<(N_NODES + 2) / 3, 64, 0, stream>>>(t2l, s2, cnt, bucket,
                                                   w2p, bm, bv, p, out);
    k_final<<<N_NODES / 2, 64, 0, stream>>>(p, cnt, bucket, out);
}

// Round 4
// 247.520 us; speedup vs baseline: 1.2525x; 1.1137x over previous
//
#include <hip/hip_runtime.h>

#define N_NODES 50000
#define N_EDGES 800000
#define CAP 64
#define ZROW 50000   // dedicated all-zero row id in t1l / t2l / p

typedef _Float16 f16;
typedef unsigned short u16;
typedef f16 f16x2 __attribute__((ext_vector_type(2)));
typedef f16 f16x4 __attribute__((ext_vector_type(4)));
typedef f16 f16x8 __attribute__((ext_vector_type(8)));
typedef float f32x4 __attribute__((ext_vector_type(4)));

#if __has_builtin(__builtin_amdgcn_fdot2)
#define FDOT2(a, b, c) __builtin_amdgcn_fdot2((a), (b), (c), false)
#else
#define FDOT2(a, b, c) ((c) + (float)(a).x * (float)(b).x + (float)(a).y * (float)(b).y)
#endif

// ---- fill: bucket pre-filled with ZROW, zero-rows zeroed, cnt zeroed ----
// grid 1600 x 256.  bucket = 3.2M u16 = 400,000 uint4 of 0xC350C350.
__global__ void k_fill(u16* __restrict__ bucket, int* __restrict__ cnt,
                       f16* __restrict__ t1l, f16* __restrict__ t2l,
                       f16* __restrict__ p) {
    int gt = blockIdx.x * 256 + threadIdx.x;
    if (gt < 400000) {
        uint4 pat = {0xC350C350u, 0xC350C350u, 0xC350C350u, 0xC350C350u};
        ((uint4*)bucket)[gt] = pat;
    }
    if (gt < N_NODES) cnt[gt] = 0;
    if (blockIdx.x == 1599) {
        int t = threadIdx.x;
        if (t < 64)       ((unsigned*)t1l)[(size_t)ZROW * 64 + t] = 0u;
        else if (t < 96)  ((unsigned*)t2l)[(size_t)ZROW * 32 + (t - 64)] = 0u;
        else if (t < 128) ((unsigned*)p)[(size_t)ZROW * 32 + (t - 96)] = 0u;
    }
}

// ---------------- build: bucket edges by dst (ushort src ids) ----------------
__global__ void k_build(const int* __restrict__ ei, int* __restrict__ cnt,
                        u16* __restrict__ bucket) {
    int e = blockIdx.x * blockDim.x + threadIdx.x;
    if (e >= N_EDGES) return;
    int s = ei[e];
    int d = ei[N_EDGES + e];
    int pos = atomicAdd(&cnt[d], 1);
    if (pos < CAP) bucket[d * CAP + pos] = (u16)s;
}

// ---------------- pack weights ----------------
// w2p[k*48+j] = j<24 ? (Wlm[k][j], Wrm[k][j]) : (Wlv[k][j-24], Wrv[k][j-24])
// w1b: MFMA B-fragments of [Wl1 | Wr1 | pad]  (15 N-tiles x 4 K-steps, K=128)
// w2b: MFMA B-fragments of [Wl2 | Wr2 | pad]  ( 6 N-tiles x 4 K-steps, K=128,
//      cols: 0..41 = Wl2, 42..83 = Wr2, 84..95 = 0; k >= 117 = 0)
// Fragment f, lane l, elem j:  frag[(f*64+l)*8+j] = W[k=(f&3)*32+(l>>4)*8+j][col=(f>>2)*16+(l&15)]
__global__ void k_packw(const float* __restrict__ Wl1, const float* __restrict__ Wr1,
                        const float* __restrict__ Wl2, const float* __restrict__ Wr2,
                        const float* __restrict__ Wlm, const float* __restrict__ Wrm,
                        const float* __restrict__ Wlv, const float* __restrict__ Wrv,
                        f16x2* __restrict__ w2p, f16* __restrict__ w1b,
                        f16* __restrict__ w2b) {
    int t = blockIdx.x * blockDim.x + threadIdx.x;
    if (t < 42 * 48) {
        int k = t / 48, j = t % 48;
        int o = (j < 24) ? j : j - 24;
        const float* L = (j < 24) ? Wlm : Wlv;
        const float* R = (j < 24) ? Wrm : Wrv;
        f16x2 w; w.x = (f16)L[k * 24 + o]; w.y = (f16)R[k * 24 + o];
        w2p[t] = w;
    }
    if (t < 15 * 4 * 64 * 8) {              // w1b
        int f = t >> 9;
        int r = t & 511;
        int lane = r >> 3, j = r & 7;
        int nt = f >> 2, s = f & 3;
        int k = s * 32 + (lane >> 4) * 8 + j;
        int col = nt * 16 + (lane & 15);
        float v = 0.f;
        if (col < 117) v = Wl1[k * 117 + col];
        else if (col < 234) v = Wr1[k * 117 + (col - 117)];
        w1b[t] = (f16)v;
    }
    if (t < 6 * 4 * 64 * 8) {               // w2b
        int f = t >> 9;
        int r = t & 511;
        int lane = r >> 3, j = r & 7;
        int nt = f >> 2, s = f & 3;
        int k = s * 32 + (lane >> 4) * 8 + j;
        int col = nt * 16 + (lane & 15);
        float v = 0.f;
        if (k < 117) {
            if (col < 42)      v = Wl2[k * 42 + col];
            else if (col < 84) v = Wr2[k * 42 + (col - 42)];
        }
        w2b[t] = (f16)v;
    }
}

// ------- MFMA gemm1: t1l = x@Wl1 (f16, stride 128, cols 117..127 zeroed)
// -------             t1r = x@Wr1 + b1 (fp32, stride 120, cols 117..119 zeroed)
__global__ __launch_bounds__(256) void k_gemm1(const float* __restrict__ x,
                        const f16* __restrict__ w1b, const float* __restrict__ b1,
                        f16* __restrict__ t1l, float* __restrict__ t1r) {
    int base = blockIdx.x * 16;
    int t = threadIdx.x;
    __shared__ __align__(16) f16 xa[16 * 128];   // 4 KB, XOR-swizzled 16B chunks
    {   // stage x tile -> f16 LDS
        int row = t >> 4, kc = t & 15;
        const float4* xp = (const float4*)(x + (size_t)(base + row) * 128 + kc * 8);
        float4 x0 = xp[0], x1 = xp[1];
        f16x8 hv;
        hv[0] = (f16)x0.x; hv[1] = (f16)x0.y; hv[2] = (f16)x0.z; hv[3] = (f16)x0.w;
        hv[4] = (f16)x1.x; hv[5] = (f16)x1.y; hv[6] = (f16)x1.z; hv[7] = (f16)x1.w;
        int byte = row * 256 + ((kc ^ (row & 7)) << 4);
        *(f16x8*)((char*)xa + byte) = hv;
    }
    __syncthreads();
    int lane = t & 63, w = t >> 6;
    int hi = lane >> 4, lo = lane & 15;
    f16x8 a[4];
#pragma unroll
    for (int s = 0; s < 4; ++s) {
        int kchunk = s * 4 + hi;
        int byte = lo * 256 + ((kchunk ^ (lo & 7)) << 4);
        a[s] = *(const f16x8*)((const char*)xa + byte);
    }
    int ntiles = (w < 3) ? 4 : 3;
    for (int i = 0; i < ntiles; ++i) {
        int nt = w * 4 + i;
        const f16x8* bp = (const f16x8*)w1b + (size_t)(nt * 4) * 64 + lane;
        f32x4 acc = {0.f, 0.f, 0.f, 0.f};
#pragma unroll
        for (int s = 0; s < 4; ++s)
            acc = __builtin_amdgcn_mfma_f32_16x16x32_f16(a[s], bp[s * 64], acc, 0, 0, 0);
        int gcol = nt * 16 + lo;
#pragma unroll
        for (int r = 0; r < 4; ++r) {
            int grow = base + hi * 4 + r;
            float val = acc[r];
            if (gcol < 117) {
                t1l[(size_t)grow * 128 + gcol] = (f16)val;
            } else if (nt == 7) {
                t1l[(size_t)grow * 128 + gcol] = (f16)0.f;
            }
            if (gcol >= 117) {
                int c2 = gcol - 117;
                if (c2 < 117)      t1r[(size_t)grow * 120 + c2] = val + b1[c2];
                else if (c2 < 120) t1r[(size_t)grow * 120 + c2] = 0.f;
            }
        }
    }
}

// ---- fused1: block = 512 (8 waves), 16-node tile.
// ---- Each wave gathers 2 nodes: h1 = relu(gather(t1l)/deg + t1r) -> f16 LDS tile.
// ---- Then 6 waves compute [t2l | s2] = h1 @ [Wl2 | Wr2] via MFMA.
__global__ __launch_bounds__(512) void k_fused1(
        const f16* __restrict__ t1l, const float* __restrict__ t1r,
        const int* __restrict__ cnt, const u16* __restrict__ bucket,
        const f16* __restrict__ w2b, const float* __restrict__ b2,
        f16* __restrict__ t2l, float* __restrict__ s2) {
    __shared__ __align__(16) f16 h1[16 * 128];   // swizzled [node][k]
    int t = threadIdx.x;
    int lane = t & 63, w = t >> 6;
    int tilebase = blockIdx.x * 16;
    int iA = tilebase + w * 2, iB = iA + 1;
    int cA = cnt[iA], cB = cnt[iB];
    int nA = cA > CAP ? CAP : cA, nB = cB > CAP ? CAP : cB;
    int idsA = (int)bucket[(size_t)iA * CAP + lane];
    int idsB = (int)bucket[(size_t)iB * CAP + lane];
    int g = (lane < 30) ? 0 : 1;
    int d = lane - 30 * g;                 // qword index; valid < 30
    bool act = (lane < 60);
    int i_my = g ? iB : iA;
    float deg = fmaxf((float)(g ? cB : cA), 1.f);
    int dd = d < 31 ? d : 31;
    int nmax = nA > nB ? nA : nB;
    float ax = 0.f, ay = 0.f, az = 0.f, aw = 0.f;
    const char* base = (const char*)t1l;
    const f16x2 e10 = {(f16)1.f, (f16)0.f};
    const f16x2 e01 = {(f16)0.f, (f16)1.f};
    for (int e0 = 0; e0 < nmax; e0 += 16) {
        f16x4 v[16];
#pragma unroll
        for (int u = 0; u < 16; ++u) {
            int e = (e0 + u) & 63;
            int ra = __builtin_amdgcn_readlane(idsA, e);
            int rb = __builtin_amdgcn_readlane(idsB, e);
            int id = g ? rb : ra;          // slots >= cnt hold ZROW (zero row)
            unsigned off = ((unsigned)id << 8) + ((unsigned)dd << 3);
            v[u] = *(const f16x4*)(base + off);
        }
#pragma unroll
        for (int u = 0; u < 16; ++u) {
            f16x2 lo = __builtin_shufflevector(v[u], v[u], 0, 1);
            f16x2 hi2 = __builtin_shufflevector(v[u], v[u], 2, 3);
            ax = FDOT2(lo, e10, ax);
            ay = FDOT2(lo, e01, ay);
            az = FDOT2(hi2, e10, az);
            aw = FDOT2(hi2, e01, aw);
        }
    }
    int trow = w * 2 + g;
    if (act) {
        float4 s = ((const float4*)(t1r + (size_t)i_my * 120))[d];
        f16x4 hv;
        hv.x = (f16)fmaxf(ax / deg + s.x, 0.f);
        hv.y = (f16)fmaxf(ay / deg + s.y, 0.f);
        hv.z = (f16)fmaxf(az / deg + s.z, 0.f);
        hv.w = (f16)fmaxf(aw / deg + s.w, 0.f);
        int chunk = d >> 1;
        int byte = trow * 256 + ((chunk ^ (trow & 7)) << 4) + ((d & 1) << 3);
        *(f16x4*)((char*)h1 + byte) = hv;
    } else {                               // lanes 60..63: zero cols 120..127
        int r2 = w * 2 + ((lane - 60) >> 1);
        int byte = r2 * 256 + ((15 ^ (r2 & 7)) << 4) + ((lane & 1) << 3);
        f16x4 z = {(f16)0.f, (f16)0.f, (f16)0.f, (f16)0.f};
        *(f16x4*)((char*)h1 + byte) = z;
    }
    __syncthreads();
    if (w < 6) {                           // MFMA: C[16 nodes][96 cols]
        int lo = lane & 15, hi = lane >> 4;
        f16x8 a[4];
#pragma unroll
        for (int s = 0; s < 4; ++s) {
            int kc = s * 4 + hi;
            int byte = lo * 256 + ((kc ^ (lo & 7)) << 4);
            a[s] = *(const f16x8*)((const char*)h1 + byte);
        }
        const f16x8* bp = (const f16x8*)w2b + (size_t)(w * 4) * 64 + lane;
        f32x4 acc = {0.f, 0.f, 0.f, 0.f};
#pragma unroll
        for (int s = 0; s < 4; ++s)
            acc = __builtin_amdgcn_mfma_f32_16x16x32_f16(a[s], bp[s * 64], acc, 0, 0, 0);
        int col = w * 16 + lo;
        if (col < 42) {
#pragma unroll
            for (int r = 0; r < 4; ++r) {
                int node = tilebase + hi * 4 + r;
                t2l[(size_t)node * 64 + col] = (f16)acc[r];
            }
        } else if (col < 84) {
            int c2 = col - 42;
            float bb = b2[c2];
#pragma unroll
            for (int r = 0; r < 4; ++r) {
                int node = tilebase + hi * 4 + r;
                s2[(size_t)node * 42 + c2] = acc[r] + bb;
            }
        }
    }
}

// ---- fused2: block = 128 (2 waves), 3 nodes/wave. h2 = relu(gather/deg + s2);
// ----         p = h2@[Wlm|Wlv] (f16), out self = h2@[Wrm|Wrv] + b.  grid = 8334
__global__ __launch_bounds__(128) void k_fused2(
        const f16* __restrict__ t2l, const float* __restrict__ s2,
        const int* __restrict__ cnt, const u16* __restrict__ bucket,
        const f16x2* __restrict__ w2p,
        const float* __restrict__ bm, const float* __restrict__ bv,
        f16* __restrict__ p, float* __restrict__ out) {
    __shared__ __align__(16) float h2[2][3][48];
    int t = threadIdx.x;
    int lane = t & 63, wv = t >> 6;
    int i0 = blockIdx.x * 6 + wv * 3;
    int iA = i0, iB = i0 + 1, iC = i0 + 2;
    bool vA = iA < N_NODES, vB = iB < N_NODES, vC = iC < N_NODES;
    int cA = vA ? cnt[iA] : 0, cB = vB ? cnt[iB] : 0, cC = vC ? cnt[iC] : 0;
    int nA = cA > CAP ? CAP : cA, nB = cB > CAP ? CAP : cB, nC = cC > CAP ? CAP : cC;
    int idsA = vA ? (int)bucket[(size_t)iA * CAP + lane] : ZROW;
    int idsB = vB ? (int)bucket[(size_t)iB * CAP + lane] : ZROW;
    int idsC = vC ? (int)bucket[(size_t)iC * CAP + lane] : ZROW;
    int g = (lane < 21) ? 0 : (lane < 42 ? 1 : 2);
    int d = lane - 21 * g;                 // dword index; valid < 21
    bool act = (lane < 63);
    int i_my = i0 + g;
    bool valid = act && (i_my < N_NODES);
    float deg = fmaxf((float)(g == 0 ? cA : (g == 1 ? cB : cC)), 1.f);
    int nmax = nA > nB ? nA : nB; if (nC > nmax) nmax = nC;
    float ax = 0.f, ay = 0.f;
    const char* base = (const char*)t2l;   // rows of 128 B
    const f16x2 e10 = {(f16)1.f, (f16)0.f};
    const f16x2 e01 = {(f16)0.f, (f16)1.f};
    for (int e0 = 0; e0 < nmax; e0 += 16) {
        f16x2 v[16];
#pragma unroll
        for (int u = 0; u < 16; ++u) {
            int e = (e0 + u) & 63;
            int ra = __builtin_amdgcn_readlane(idsA, e);
            int rb = __builtin_amdgcn_readlane(idsB, e);
            int rc = __builtin_amdgcn_readlane(idsC, e);
            int id = (g == 0) ? ra : ((g == 1) ? rb : rc);
            unsigned off = ((unsigned)id << 7) + ((unsigned)d << 2);
            v[u] = *(const f16x2*)(base + off);
        }
#pragma unroll
        for (int u = 0; u < 16; ++u) {
            ax = FDOT2(v[u], e10, ax);
            ay = FDOT2(v[u], e01, ay);
        }
    }
    if (valid && d < 21) {
        float2 s = ((const float2*)(s2 + (size_t)i_my * 42))[d];
        h2[wv][g][2 * d]     = fmaxf(ax / deg + s.x, 0.f);
        h2[wv][g][2 * d + 1] = fmaxf(ay / deg + s.y, 0.f);
    }
    __syncthreads();
    int j = lane;
    if (j < 48) {
        int o = (j < 24) ? j : j - 24;
        float bias = (j < 24) ? bm[o] : bv[o];
        float pA = 0.f, pB = 0.f, pC = 0.f, qA = 0.f, qB = 0.f, qC = 0.f;
        const float4* hA = (const float4*)&h2[wv][0][0];
        const float4* hB = (const float4*)&h2[wv][1][0];
        const float4* hC = (const float4*)&h2[wv][2][0];
#pragma unroll 2
        for (int kk = 0; kk < 10; ++kk) {
            float4 a = hA[kk], b = hB[kk], c = hC[kk];
            float av[4] = {a.x, a.y, a.z, a.w};
            float bv4[4] = {b.x, b.y, b.z, b.w};
            float cv[4] = {c.x, c.y, c.z, c.w};
#pragma unroll
            for (int u = 0; u < 4; ++u) {
                int k = 4 * kk + u;
                f16x2 wvv = w2p[k * 48 + j];
                float wl = (float)wvv.x, wr = (float)wvv.y;
                pA = fmaf(av[u], wl, pA);  qA = fmaf(av[u], wr, qA);
                pB = fmaf(bv4[u], wl, pB); qB = fmaf(bv4[u], wr, qB);
                pC = fmaf(cv[u], wl, pC);  qC = fmaf(cv[u], wr, qC);
            }
        }
        for (int k = 40; k < 42; ++k) {
            f16x2 wvv = w2p[k * 48 + j];
            float wl = (float)wvv.x, wr = (float)wvv.y;
            pA = fmaf(h2[wv][0][k], wl, pA); qA = fmaf(h2[wv][0][k], wr, qA);
            pB = fmaf(h2[wv][1][k], wl, pB); qB = fmaf(h2[wv][1][k], wr, qB);
            pC = fmaf(h2[wv][2][k], wl, pC); qC = fmaf(h2[wv][2][k], wr, qC);
        }
        size_t half = (j < 24) ? 0 : (size_t)N_NODES * 24;
        if (vA) { p[(size_t)iA * 64 + j] = (f16)pA; out[half + (size_t)iA * 24 + o] = qA + bias; }
        if (vB) { p[(size_t)iB * 64 + j] = (f16)pB; out[half + (size_t)iB * 24 + o] = qB + bias; }
        if (vC) { p[(size_t)iC * 64 + j] = (f16)pC; out[half + (size_t)iC * 24 + o] = qC + bias; }
    }
}

// ---- final: block = 128 (2 waves), 2 nodes/wave. Pure gather of p + RMW. grid 12500
__global__ __launch_bounds__(128) void k_final(
        const f16* __restrict__ p, const int* __restrict__ cnt,
        const u16* __restrict__ bucket, float* __restrict__ out) {
    int t = threadIdx.x;
    int lane = t & 63, wv = t >> 6;
    int iA = blockIdx.x * 4 + wv * 2, iB = iA + 1;
    int cA = cnt[iA], cB = cnt[iB];
    int nA = cA > CAP ? CAP : cA, nB = cB > CAP ? CAP : cB;
    int idsA = (int)bucket[(size_t)iA * CAP + lane];
    int idsB = (int)bucket[(size_t)iB * CAP + lane];
    int g = (lane < 24) ? 0 : 1;
    int d = lane - 24 * g;                 // dword index; valid < 24
    bool act = (lane < 48);
    int i_my = g ? iB : iA;
    float deg = fmaxf((float)(g ? cB : cA), 1.f);
    int dd = d < 31 ? d : 31;
    int nmax = nA > nB ? nA : nB;
    float ax = 0.f, ay = 0.f;
    const char* base = (const char*)p;     // rows of 128 B
    const f16x2 e10 = {(f16)1.f, (f16)0.f};
    const f16x2 e01 = {(f16)0.f, (f16)1.f};
    for (int e0 = 0; e0 < nmax; e0 += 16) {
        f16x2 v[16];
#pragma unroll
        for (int u = 0; u < 16; ++u) {
            int e = (e0 + u) & 63;
            int ra = __builtin_amdgcn_readlane(idsA, e);
            int rb = __builtin_amdgcn_readlane(idsB, e);
            int id = g ? rb : ra;
            unsigned off = ((unsigned)id << 7) + ((unsigned)dd << 2);
            v[u] = *(const f16x2*)(base + off);
        }
#pragma unroll
        for (int u = 0; u < 16; ++u) {
            ax = FDOT2(v[u], e10, ax);
            ay = FDOT2(v[u], e01, ay);
        }
    }
    if (act) {
        float mx = ax / deg, my = ay / deg;
        size_t addr = (d < 12) ? ((size_t)i_my * 24 + 2 * d)
                               : ((size_t)N_NODES * 24 + (size_t)i_my * 24 + 2 * (d - 12));
        float2 s = *(const float2*)(out + addr);
        float2 r; r.x = s.x + mx; r.y = s.y + my;
        *(float2*)(out + addr) = r;
    }
}

extern "C" void kernel_launch(void* const* d_in, const int* in_sizes, int n_in,
                              void* d_out, int out_size, void* d_ws, size_t ws_size,
                              hipStream_t stream) {
    const float* x   = (const float*)d_in[0];
    const int*   ei  = (const int*)d_in[1];
    const float* Wl1 = (const float*)d_in[2];
    const float* Wr1 = (const float*)d_in[3];
    const float* b1  = (const float*)d_in[4];
    const float* Wl2 = (const float*)d_in[5];
    const float* Wr2 = (const float*)d_in[6];
    const float* b2  = (const float*)d_in[7];
    const float* Wlm = (const float*)d_in[8];
    const float* Wrm = (const float*)d_in[9];
    const float* bm  = (const float*)d_in[10];
    const float* Wlv = (const float*)d_in[11];
    const float* Wrv = (const float*)d_in[12];
    const float* bv  = (const float*)d_in[13];
    float* out = (float*)d_out;

    // workspace layout (bytes):
    //   cnt    @ 0          : 200,000                  -> pad 204,800
    //   bucket @ 204,800    : 50000*64*2 =  6,400,000  ->  6,604,800
    //   t1l    @ 6,604,800  : 50001*128*2= 12,800,256  -> 19,405,312 (padded)
    //   t1r    @ 19,405,312 : 50000*120*4= 24,000,000  -> 43,405,312
    //   t2l    @ 43,405,312 : 50001*64*2 =  6,400,128  -> 49,805,824 (padded)
    //   s2     @ 49,805,824 : 50000*42*4 =  8,400,000  -> 58,205,824
    //     (w1b 61,440 B OVERLAYS s2: consumed by k_gemm1 before fused1 writes s2)
    //   p      @ 58,205,824 : 50001*64*2 =  6,400,128  -> 64,606,208 (padded)
    //   w2p    @ 64,606,208 : 42*48*4    =      8,064  -> 64,614,400 (padded)
    //   w2b    @ 64,614,400 : 6*4*64*8*2 =     24,576  -> 64,638,976
    char* ws = (char*)d_ws;
    int*   cnt    = (int*)(ws);
    u16*   bucket = (u16*)(ws + 204800);
    f16*   t1l    = (f16*)(ws + 6604800);
    float* t1r    = (float*)(ws + 19405312);
    f16*   t2l    = (f16*)(ws + 43405312);
    float* s2     = (float*)(ws + 49805824);
    f16*   w1b    = (f16*)(ws + 49805824);   // overlays s2 (dead until fused1)
    f16*   p      = (f16*)(ws + 58205824);
    f16x2* w2p    = (f16x2*)(ws + 64606208);
    f16*   w2b    = (f16*)(ws + 64614400);

    k_fill<<<1600, 256, 0, stream>>>(bucket, cnt, t1l, t2l, p);
    k_packw<<<120, 256, 0, stream>>>(Wl1, Wr1, Wl2, Wr2, Wlm, Wrm, Wlv, Wrv,
                                     w2p, w1b, w2b);
    k_build<<<(N_EDGES + 255) / 256, 256, 0, stream>>>(ei, cnt, bucket);
    k_gemm1<<<N_NODES / 16, 256, 0, stream>>>(x, w1b, b1, t1l, t1r);
    k_fused1<<<N_NODES / 16, 512, 0, stream>>>(t1l, t1r, cnt, bucket, w2b, b2, t2l, s2);
    k_fused2<<<(N_NODES + 5) / 6, 128, 0, stream>>>(t2l, s2, cnt, bucket,
                                                    w2p, bm, bv, p, out);
    k_final<<<N_NODES / 4, 128, 0, stream>>>(p, cnt, bucket, out);
}

// Round 5
// 209.384 us; speedup vs baseline: 1.4806x; 1.1821x over previous
//
#include <hip/hip_runtime.h>

#define N_NODES 50000
#define N_EDGES 800000
#define CAP 64
#define ZROW 50000   // dedicated all-zero row id in t1l / t2l / p

typedef _Float16 f16;
typedef unsigned short u16;
typedef f16 f16x2 __attribute__((ext_vector_type(2)));
typedef f16 f16x4 __attribute__((ext_vector_type(4)));
typedef f16 f16x8 __attribute__((ext_vector_type(8)));
typedef float f32x4 __attribute__((ext_vector_type(4)));

#if __has_builtin(__builtin_amdgcn_fdot2)
#define FDOT2(a, b, c) __builtin_amdgcn_fdot2((a), (b), (c), false)
#else
#define FDOT2(a, b, c) ((c) + (float)(a).x * (float)(b).x + (float)(a).y * (float)(b).y)
#endif

// ---- fillpack: bucket prefill (ZROW pattern), cnt zero, zero-rows, weight packs ----
// w1b: B-frags of [Wl1 | Wr1 | pad]      15 tiles x 4 K-steps (K=128)
// w2b: B-frags of [Wl2 |0(6)| Wr2 |0(6)]  6 tiles x 4 K-steps (K=128, k>=117 -> 0)
// w3b: B-frags of [Wlm|Wlv|Wrm|Wrv]       6 tiles x 2 K-steps (K=64,  k>=42  -> 0)
// Fragment f, lane l, elem j: frag[(f*64+l)*8+j] = W[k=(f%S)*32+(l>>4)*8+j][col=(f/S)*16+(l&15)]
__global__ void k_fillpack(u16* __restrict__ bucket, int* __restrict__ cnt,
                           f16* __restrict__ t1l, f16* __restrict__ t2l,
                           f16* __restrict__ p,
                           const float* __restrict__ Wl1, const float* __restrict__ Wr1,
                           const float* __restrict__ Wl2, const float* __restrict__ Wr2,
                           const float* __restrict__ Wlm, const float* __restrict__ Wrm,
                           const float* __restrict__ Wlv, const float* __restrict__ Wrv,
                           f16* __restrict__ w1b, f16* __restrict__ w2b,
                           f16* __restrict__ w3b) {
    int gt = blockIdx.x * 256 + threadIdx.x;
    if (gt < 400000) {
        uint4 pat = {0xC350C350u, 0xC350C350u, 0xC350C350u, 0xC350C350u};
        ((uint4*)bucket)[gt] = pat;
    }
    if (gt < N_NODES) cnt[gt] = 0;
    if (blockIdx.x == 1599) {
        int t = threadIdx.x;
        if (t < 64)       ((unsigned*)t1l)[(size_t)ZROW * 64 + t] = 0u;
        else if (t < 96)  ((unsigned*)t2l)[(size_t)ZROW * 32 + (t - 64)] = 0u;
        else if (t < 128) ((unsigned*)p)[(size_t)ZROW * 32 + (t - 96)] = 0u;
    }
    if (gt < 15 * 4 * 64 * 8) {              // w1b
        int f = gt >> 9, r = gt & 511;
        int lane = r >> 3, j = r & 7;
        int nt = f >> 2, s = f & 3;
        int k = s * 32 + (lane >> 4) * 8 + j;
        int col = nt * 16 + (lane & 15);
        float v = 0.f;
        if (col < 117) v = Wl1[k * 117 + col];
        else if (col < 234) v = Wr1[k * 117 + (col - 117)];
        w1b[gt] = (f16)v;
    }
    if (gt < 6 * 4 * 64 * 8) {               // w2b
        int f = gt >> 9, r = gt & 511;
        int lane = r >> 3, j = r & 7;
        int nt = f >> 2, s = f & 3;
        int k = s * 32 + (lane >> 4) * 8 + j;
        int col = nt * 16 + (lane & 15);
        float v = 0.f;
        if (k < 117) {
            if (col < 42)                     v = Wl2[k * 42 + col];
            else if (col >= 48 && col < 90)   v = Wr2[k * 42 + (col - 48)];
        }
        w2b[gt] = (f16)v;
    }
    if (gt < 6 * 2 * 64 * 8) {               // w3b
        int f = gt >> 9, r = gt & 511;
        int lane = r >> 3, j = r & 7;
        int ct = f >> 1, s = f & 1;
        int k = s * 32 + (lane >> 4) * 8 + j;
        int col = ct * 16 + (lane & 15);
        float v = 0.f;
        if (k < 42) {
            if (col < 24)      v = Wlm[k * 24 + col];
            else if (col < 48) v = Wlv[k * 24 + (col - 24)];
            else if (col < 72) v = Wrm[k * 24 + (col - 48)];
            else               v = Wrv[k * 24 + (col - 72)];
        }
        w3b[gt] = (f16)v;
    }
}

// ------- k_bg: edge bucketing FUSED with MFMA gemm1. grid 3125 x 256 (= 800k threads)
// ------- t1l = x@Wl1 (f16, stride 128, cols 117..127 zeroed)
// ------- t1r = x@Wr1 + b1 (fp32, stride 120, cols 117..119 zeroed)
__global__ __launch_bounds__(256) void k_bg(const int* __restrict__ ei,
                        int* __restrict__ cnt, u16* __restrict__ bucket,
                        const float* __restrict__ x,
                        const f16* __restrict__ w1b, const float* __restrict__ b1,
                        f16* __restrict__ t1l, float* __restrict__ t1r) {
    int t = threadIdx.x;
    int e = blockIdx.x * 256 + t;                // exactly N_EDGES threads
    int se = ei[e];
    int de = ei[N_EDGES + e];
    int pos = atomicAdd(&cnt[de], 1);            // latency hidden by GEMM below

    int base = blockIdx.x * 16;
    __shared__ __align__(16) f16 xa[16 * 128];   // 4 KB, XOR-swizzled 16B chunks
    {   // stage x tile -> f16 LDS
        int row = t >> 4, kc = t & 15;
        const float4* xp = (const float4*)(x + (size_t)(base + row) * 128 + kc * 8);
        float4 x0 = xp[0], x1 = xp[1];
        f16x8 hv;
        hv[0] = (f16)x0.x; hv[1] = (f16)x0.y; hv[2] = (f16)x0.z; hv[3] = (f16)x0.w;
        hv[4] = (f16)x1.x; hv[5] = (f16)x1.y; hv[6] = (f16)x1.z; hv[7] = (f16)x1.w;
        int byte = row * 256 + ((kc ^ (row & 7)) << 4);
        *(f16x8*)((char*)xa + byte) = hv;
    }
    __syncthreads();
    int lane = t & 63, w = t >> 6;
    int hi = lane >> 4, lo = lane & 15;
    f16x8 a[4];
#pragma unroll
    for (int s = 0; s < 4; ++s) {
        int kchunk = s * 4 + hi;
        int byte = lo * 256 + ((kchunk ^ (lo & 7)) << 4);
        a[s] = *(const f16x8*)((const char*)xa + byte);
    }
    int ntiles = (w < 3) ? 4 : 3;
    for (int i = 0; i < ntiles; ++i) {
        int nt = w * 4 + i;
        const f16x8* bp = (const f16x8*)w1b + (size_t)(nt * 4) * 64 + lane;
        f32x4 acc = {0.f, 0.f, 0.f, 0.f};
#pragma unroll
        for (int s = 0; s < 4; ++s)
            acc = __builtin_amdgcn_mfma_f32_16x16x32_f16(a[s], bp[s * 64], acc, 0, 0, 0);
        int gcol = nt * 16 + lo;
#pragma unroll
        for (int r = 0; r < 4; ++r) {
            int grow = base + hi * 4 + r;
            float val = acc[r];
            if (gcol < 117) {
                t1l[(size_t)grow * 128 + gcol] = (f16)val;
            } else if (nt == 7) {
                t1l[(size_t)grow * 128 + gcol] = (f16)0.f;
            }
            if (gcol >= 117) {
                int c2 = gcol - 117;
                if (c2 < 117)      t1r[(size_t)grow * 120 + c2] = val + b1[c2];
                else if (c2 < 120) t1r[(size_t)grow * 120 + c2] = 0.f;
            }
        }
    }
    if (pos < CAP) bucket[de * CAP + pos] = (u16)se;   // commit after GEMM
}

// ---- fused1: block 512 (8 waves), 32-node tile. Wave gathers 4 nodes (15 lanes x
// ---- 16B each): h1 = relu(gather(t1l)/deg + t1r) -> swizzled f16 LDS [32][128].
// ---- Then 12 MFMA jobs (2 row-halves x 6 col-tiles) over [Wl2|0|Wr2|0]. grid 1563
__global__ __launch_bounds__(512) void k_fused1(
        const f16* __restrict__ t1l, const float* __restrict__ t1r,
        const int* __restrict__ cnt, const u16* __restrict__ bucket,
        const f16* __restrict__ w2b, const float* __restrict__ b2,
        f16* __restrict__ t2l, float* __restrict__ s2) {
    __shared__ __align__(16) f16 h1[32 * 128];   // 8 KB
    __shared__ __align__(16) u16 ids[32 * 72];   // 4.6 KB, padded rows
    int t = threadIdx.x;
    int lane = t & 63, w = t >> 6;
    int tilebase = blockIdx.x * 32;
    if (t < 256) {                               // stage 32 bucket rows
        uint4 q = ((const uint4*)(bucket + (size_t)tilebase * CAP))[t];
        int nl = t >> 3, c = t & 7;
        *(uint4*)(ids + nl * 72 + c * 8) = q;
    }
    int g = (lane < 60) ? (lane / 15) : 3;
    int d = (lane < 60) ? (lane - g * 15) : 14;
    int nl = w * 4 + g;
    int i_my = tilebase + nl;
    int c = (i_my < N_NODES && lane < 60) ? cnt[i_my] : 0;
    int n = min(c, CAP);
    float deg = fmaxf((float)c, 1.f);
    int n0 = __builtin_amdgcn_readlane(n, 0),  n1 = __builtin_amdgcn_readlane(n, 15);
    int n2 = __builtin_amdgcn_readlane(n, 30), n3 = __builtin_amdgcn_readlane(n, 45);
    int nmax = max(max(n0, n1), max(n2, n3));
    __syncthreads();
    float acc[8] = {0.f, 0.f, 0.f, 0.f, 0.f, 0.f, 0.f, 0.f};
    const char* tb = (const char*)t1l;
    unsigned doff = (unsigned)d * 16;
    const f16x2 e10 = {(f16)1.f, (f16)0.f};
    const f16x2 e01 = {(f16)0.f, (f16)1.f};
    int idb = nl * 72;
    for (int e0 = 0; e0 < nmax; e0 += 8) {
        f16x8 v[8];
#pragma unroll
        for (int u = 0; u < 8; ++u) {
            unsigned id = ids[idb + e0 + u];     // slots >= count hold ZROW
            v[u] = *(const f16x8*)(tb + id * 256u + doff);
        }
#pragma unroll
        for (int u = 0; u < 8; ++u) {
            const f16x2* pv = (const f16x2*)&v[u];
#pragma unroll
            for (int j = 0; j < 4; ++j) {
                acc[2 * j]     = FDOT2(pv[j], e10, acc[2 * j]);
                acc[2 * j + 1] = FDOT2(pv[j], e01, acc[2 * j + 1]);
            }
        }
    }
    if (lane < 60) {
        int i_ld = (i_my < N_NODES) ? i_my : 0;
        const float4* sp = (const float4*)(t1r + (size_t)i_ld * 120 + 8 * d);
        float4 s0 = sp[0], s1 = sp[1];
        float sv[8] = {s0.x, s0.y, s0.z, s0.w, s1.x, s1.y, s1.z, s1.w};
        f16x8 hv;
#pragma unroll
        for (int j = 0; j < 8; ++j) hv[j] = (f16)fmaxf(acc[j] / deg + sv[j], 0.f);
        int byte = nl * 256 + ((d ^ (nl & 7)) << 4);
        *(f16x8*)((char*)h1 + byte) = hv;
    } else {                                     // zero chunk 15 (cols 120..127)
        int row = w * 4 + (lane - 60);
        int byte = row * 256 + ((15 ^ (row & 7)) << 4);
        f16x8 z = {};
        *(f16x8*)((char*)h1 + byte) = z;
    }
    __syncthreads();
    int lo = lane & 15, hi = lane >> 4;
    for (int jj = w; jj < 12; jj += 8) {
        int ct = jj >> 1, rh = jj & 1;
        int row = rh * 16 + lo;
        f16x8 a[4];
#pragma unroll
        for (int s = 0; s < 4; ++s) {
            int kc = s * 4 + hi;
            a[s] = *(const f16x8*)((const char*)h1 + row * 256 + ((kc ^ (row & 7)) << 4));
        }
        const f16x8* bp = (const f16x8*)w2b + (size_t)(ct * 4) * 64 + lane;
        f32x4 acc4 = {0.f, 0.f, 0.f, 0.f};
#pragma unroll
        for (int s = 0; s < 4; ++s)
            acc4 = __builtin_amdgcn_mfma_f32_16x16x32_f16(a[s], bp[s * 64], acc4, 0, 0, 0);
        int col = ct * 16 + lo;
#pragma unroll
        for (int r = 0; r < 4; ++r) {
            int node = tilebase + rh * 16 + hi * 4 + r;
            if (node < N_NODES) {
                if (col < 48)      t2l[(size_t)node * 64 + col] = (f16)acc4[r];
                else if (col < 90) s2[(size_t)node * 42 + (col - 48)] = acc4[r] + b2[col - 48];
            }
        }
    }
}

// ---- fused2: block 128 (2 waves), 16-node tile. Wave gathers 8 nodes (6 lanes x
// ---- 16B = cols 0..47 of t2l, 42..47 are zeros). h2 -> swizzled LDS [16][64].
// ---- MFMA K=64 over [Wlm|Wlv|Wrm|Wrv]: cols<48 -> p, cols>=48 -> out self. grid 3125
__global__ __launch_bounds__(128) void k_fused2(
        const f16* __restrict__ t2l, const float* __restrict__ s2,
        const int* __restrict__ cnt, const u16* __restrict__ bucket,
        const f16* __restrict__ w3b,
        const float* __restrict__ bm, const float* __restrict__ bv,
        f16* __restrict__ p, float* __restrict__ out) {
    __shared__ __align__(16) f16 h2[16 * 64];    // 2 KB
    __shared__ __align__(16) u16 ids[16 * 72];
    int t = threadIdx.x;
    int lane = t & 63, wv = t >> 6;
    int nb = blockIdx.x * 16;
    {
        uint4 q = ((const uint4*)(bucket + (size_t)nb * CAP))[t];
        int nl = t >> 3, c = t & 7;
        *(uint4*)(ids + nl * 72 + c * 8) = q;
    }
    int g = (lane < 48) ? (lane / 6) : 7;
    int d = (lane < 48) ? (lane - g * 6) : 5;
    int nl = wv * 8 + g;
    int i_my = nb + nl;
    int c = (lane < 48) ? cnt[i_my] : 0;
    int n = min(c, CAP);
    float deg = fmaxf((float)c, 1.f);
    int nmax = n;
#pragma unroll
    for (int m = 1; m < 64; m <<= 1) nmax = max(nmax, __shfl_xor(nmax, m));
    __syncthreads();
    float acc[8] = {0.f, 0.f, 0.f, 0.f, 0.f, 0.f, 0.f, 0.f};
    const char* tb = (const char*)t2l;
    unsigned doff = (unsigned)d * 16;
    const f16x2 e10 = {(f16)1.f, (f16)0.f};
    const f16x2 e01 = {(f16)0.f, (f16)1.f};
    int idb = nl * 72;
    for (int e0 = 0; e0 < nmax; e0 += 8) {
        f16x8 v[8];
#pragma unroll
        for (int u = 0; u < 8; ++u) {
            unsigned id = ids[idb + e0 + u];
            v[u] = *(const f16x8*)(tb + id * 128u + doff);
        }
#pragma unroll
        for (int u = 0; u < 8; ++u) {
            const f16x2* pv = (const f16x2*)&v[u];
#pragma unroll
            for (int j = 0; j < 4; ++j) {
                acc[2 * j]     = FDOT2(pv[j], e10, acc[2 * j]);
                acc[2 * j + 1] = FDOT2(pv[j], e01, acc[2 * j + 1]);
            }
        }
    }
    if (lane < 48) {
        float sv[8];
        if (d < 5) {
            const float4* sp = (const float4*)(s2 + (size_t)i_my * 42 + 8 * d);
            float4 s0 = sp[0], s1 = sp[1];
            sv[0] = s0.x; sv[1] = s0.y; sv[2] = s0.z; sv[3] = s0.w;
            sv[4] = s1.x; sv[5] = s1.y; sv[6] = s1.z; sv[7] = s1.w;
        } else {
            float2 s0 = *(const float2*)(s2 + (size_t)i_my * 42 + 40);
            sv[0] = s0.x; sv[1] = s0.y;
            sv[2] = sv[3] = sv[4] = sv[5] = sv[6] = sv[7] = 0.f;
        }
        f16x8 hv;
#pragma unroll
        for (int j = 0; j < 8; ++j) hv[j] = (f16)fmaxf(acc[j] / deg + sv[j], 0.f);
        int byte = nl * 128 + ((d ^ (nl & 7)) << 4);
        *(f16x8*)((char*)h2 + byte) = hv;
    } else {                                     // zero chunks 6,7 (cols 48..63)
        int j = lane - 48;
        int row = wv * 8 + (j >> 1);
        int chunk = 6 + (j & 1);
        int byte = row * 128 + ((chunk ^ (row & 7)) << 4);
        f16x8 z = {};
        *(f16x8*)((char*)h2 + byte) = z;
    }
    __syncthreads();
    int lo = lane & 15, hi = lane >> 4;
    f16x8 a2[2];
#pragma unroll
    for (int s = 0; s < 2; ++s) {
        int kc = s * 4 + hi;
        a2[s] = *(const f16x8*)((const char*)h2 + lo * 128 + ((kc ^ (lo & 7)) << 4));
    }
#pragma unroll
    for (int i = 0; i < 3; ++i) {
        int ct = wv * 3 + i;
        const f16x8* bp = (const f16x8*)w3b + (size_t)(ct * 2) * 64 + lane;
        f32x4 acc4 = {0.f, 0.f, 0.f, 0.f};
        acc4 = __builtin_amdgcn_mfma_f32_16x16x32_f16(a2[0], bp[0], acc4, 0, 0, 0);
        acc4 = __builtin_amdgcn_mfma_f32_16x16x32_f16(a2[1], bp[64], acc4, 0, 0, 0);
        int col = ct * 16 + lo;
#pragma unroll
        for (int r = 0; r < 4; ++r) {
            int node = nb + hi * 4 + r;
            if (col < 48) {
                p[(size_t)node * 64 + col] = (f16)acc4[r];
            } else {
                int o = col - 48;
                if (o < 24) out[(size_t)node * 24 + o] = acc4[r] + bm[o];
                else out[(size_t)N_NODES * 24 + (size_t)node * 24 + (o - 24)] = acc4[r] + bv[o - 24];
            }
        }
    }
}

// ---- final: block 128 (2 waves), 20 nodes/block. Wave gathers 10 nodes (6 lanes x
// ---- 16B = p cols 0..47) + RMW of self term in out. grid 2500
__global__ __launch_bounds__(128) void k_final(
        const f16* __restrict__ p, const int* __restrict__ cnt,
        const u16* __restrict__ bucket, float* __restrict__ out) {
    __shared__ __align__(16) u16 ids[20 * 72];
    int t = threadIdx.x;
    int lane = t & 63, wv = t >> 6;
    int nb = blockIdx.x * 20;
    for (int s = t; s < 160; s += 128) {
        uint4 q = ((const uint4*)(bucket + (size_t)nb * CAP))[s];
        int nl = s >> 3, c = s & 7;
        *(uint4*)(ids + nl * 72 + c * 8) = q;
    }
    int g = (lane < 60) ? (lane / 6) : 9;
    int d = (lane < 60) ? (lane - g * 6) : 5;
    int nl = wv * 10 + g;
    int i_my = nb + nl;
    int c = (lane < 60) ? cnt[i_my] : 0;
    int n = min(c, CAP);
    float deg = fmaxf((float)c, 1.f);
    int nmax = n;
#pragma unroll
    for (int m = 1; m < 64; m <<= 1) nmax = max(nmax, __shfl_xor(nmax, m));
    __syncthreads();
    float acc[8] = {0.f, 0.f, 0.f, 0.f, 0.f, 0.f, 0.f, 0.f};
    const char* pb = (const char*)p;
    unsigned doff = (unsigned)d * 16;
    const f16x2 e10 = {(f16)1.f, (f16)0.f};
    const f16x2 e01 = {(f16)0.f, (f16)1.f};
    int idb = nl * 72;
    for (int e0 = 0; e0 < nmax; e0 += 8) {
        f16x8 v[8];
#pragma unroll
        for (int u = 0; u < 8; ++u) {
            unsigned id = ids[idb + e0 + u];
            v[u] = *(const f16x8*)(pb + id * 128u + doff);
        }
#pragma unroll
        for (int u = 0; u < 8; ++u) {
            const f16x2* pv = (const f16x2*)&v[u];
#pragma unroll
            for (int j = 0; j < 4; ++j) {
                acc[2 * j]     = FDOT2(pv[j], e10, acc[2 * j]);
                acc[2 * j + 1] = FDOT2(pv[j], e01, acc[2 * j + 1]);
            }
        }
    }
    if (lane < 60) {
        float rdeg = 1.f / deg;
        size_t base = (d < 3) ? ((size_t)i_my * 24 + 8 * d)
                              : ((size_t)N_NODES * 24 + (size_t)i_my * 24 + 8 * (d - 3));
        float4 o0 = *(const float4*)(out + base);
        float4 o1 = *(const float4*)(out + base + 4);
        o0.x += acc[0] * rdeg; o0.y += acc[1] * rdeg;
        o0.z += acc[2] * rdeg; o0.w += acc[3] * rdeg;
        o1.x += acc[4] * rdeg; o1.y += acc[5] * rdeg;
        o1.z += acc[6] * rdeg; o1.w += acc[7] * rdeg;
        *(float4*)(out + base) = o0;
        *(float4*)(out + base + 4) = o1;
    }
}

extern "C" void kernel_launch(void* const* d_in, const int* in_sizes, int n_in,
                              void* d_out, int out_size, void* d_ws, size_t ws_size,
                              hipStream_t stream) {
    const float* x   = (const float*)d_in[0];
    const int*   ei  = (const int*)d_in[1];
    const float* Wl1 = (const float*)d_in[2];
    const float* Wr1 = (const float*)d_in[3];
    const float* b1  = (const float*)d_in[4];
    const float* Wl2 = (const float*)d_in[5];
    const float* Wr2 = (const float*)d_in[6];
    const float* b2  = (const float*)d_in[7];
    const float* Wlm = (const float*)d_in[8];
    const float* Wrm = (const float*)d_in[9];
    const float* bm  = (const float*)d_in[10];
    const float* Wlv = (const float*)d_in[11];
    const float* Wrv = (const float*)d_in[12];
    const float* bv  = (const float*)d_in[13];
    float* out = (float*)d_out;

    // workspace layout (bytes):
    //   cnt    @ 0          : 200,000                  -> pad 204,800
    //   bucket @ 204,800    : 50000*64*2 =  6,400,000  ->  6,604,800
    //   t1l    @ 6,604,800  : 50001*128*2= 12,800,256  -> 19,405,312 (padded)
    //   t1r    @ 19,405,312 : 50000*120*4= 24,000,000  -> 43,405,312
    //   t2l    @ 43,405,312 : 50001*64*2 =  6,400,128  -> 49,805,824 (padded)
    //   s2     @ 49,805,824 : 50000*42*4 =  8,400,000  -> 58,205,824
    //     (w1b 61,440 B OVERLAYS s2: consumed by k_bg before fused1 writes s2)
    //   p      @ 58,205,824 : 50001*64*2 =  6,400,128  -> 64,606,208 (padded)
    //   w2b    @ 64,606,208 : 6*4*64*8*2 =     24,576  -> 64,630,784
    //   w3b    @ 64,630,784 : 6*2*64*8*2 =     12,288  -> 64,643,072
    char* ws = (char*)d_ws;
    int*   cnt    = (int*)(ws);
    u16*   bucket = (u16*)(ws + 204800);
    f16*   t1l    = (f16*)(ws + 6604800);
    float* t1r    = (float*)(ws + 19405312);
    f16*   t2l    = (f16*)(ws + 43405312);
    float* s2     = (float*)(ws + 49805824);
    f16*   w1b    = (f16*)(ws + 49805824);   // overlays s2 (dead until fused1)
    f16*   p      = (f16*)(ws + 58205824);
    f16*   w2b    = (f16*)(ws + 64606208);
    f16*   w3b    = (f16*)(ws + 64630784);

    k_fillpack<<<1600, 256, 0, stream>>>(bucket, cnt, t1l, t2l, p,
                                         Wl1, Wr1, Wl2, Wr2, Wlm, Wrm, Wlv, Wrv,
                                         w1b, w2b, w3b);
    k_bg<<<3125, 256, 0, stream>>>(ei, cnt, bucket, x, w1b, b1, t1l, t1r);
    k_fused1<<<1563, 512, 0, stream>>>(t1l, t1r, cnt, bucket, w2b, b2, t2l, s2);
    k_fused2<<<3125, 128, 0, stream>>>(t2l, s2, cnt, bucket, w3b, bm, bv, p, out);
    k_final<<<2500, 128, 0, stream>>>(p, cnt, bucket, out);
}